// Round 14
// baseline (2043.987 us; speedup 1.0000x reference)
//
#include <hip/hip_runtime.h>
#include <hip/hip_bf16.h>
#include <math.h>

#define B_ 8
#define N_TOK 4096
#define C_ 768
#define H_ 12
#define HD_ 64
#define M_ 266
#define TC_ 2304
#define BH_ 96
#define ROWS_ 32768

#define M2 288          // padded m-dim (9 ksteps x 32)
#define MP 296          // LDS m-stride (u16), 16B-aligned rows
#define KVS 72          // LDS stride for K/Vt (u16), 16B-aligned rows
#define K1S 40          // LDS stride for k1 half-buffer (u16)

#define DN 0.35355339059327373f      // 1/sqrt(sqrt(64))
#define RATIO 0.06131393394849658f   // 1/sqrt(266)
#define FEPS 1e-4f
#define NEG_INF -3.0e38f

typedef __attribute__((ext_vector_type(4))) float f32x4;
typedef __attribute__((ext_vector_type(8))) short bf16x8;

__device__ __forceinline__ float bf2f(unsigned short u) {
  return __uint_as_float(((unsigned int)u) << 16);
}
__device__ __forceinline__ unsigned short f2bf(float f) {
  unsigned int x = __float_as_uint(f);
  unsigned int r = (x + 0x7fffu + ((x >> 16) & 1u)) >> 16;
  return (unsigned short)r;
}

#define GLOAD_LDS16(g, l) \
  __builtin_amdgcn_global_load_lds( \
      (const __attribute__((address_space(1))) void*)(g), \
      (__attribute__((address_space(3))) void*)(l), 16, 0, 0)

// ---------------- prep: cast f32 -> bf16 elementwise ----------------
__global__ __launch_bounds__(256) void cast_bf16(
    const float* __restrict__ src, unsigned short* __restrict__ dst, int n)
{
  int i = (blockIdx.x * 256 + threadIdx.x) * 4;
  if (i < n) {
    float4 v = *(const float4*)&src[i];
    ushort4 u;
    u.x = f2bf(v.x); u.y = f2bf(v.y); u.z = f2bf(v.z); u.w = f2bf(v.w);
    *(ushort4*)&dst[i] = u;
  }
}

// ---------------- prep: P [266][64] f32 -> Pbf [288][64] bf16 (zero-padded) ----
__global__ __launch_bounds__(256) void cast_pbf(
    const float* __restrict__ P, unsigned short* __restrict__ Pbf)
{
  int idx = blockIdx.x * 256 + threadIdx.x;
  if (idx < M2 * 64) {
    int m = idx >> 6;
    Pbf[idx] = (m < M_) ? f2bf(P[idx]) : (unsigned short)0;
  }
}

// ---------------- prep: transpose + cast: src[R][Ccols] f32 -> dst[Ccols][R] bf16 ----
__global__ __launch_bounds__(256) void transpose_cast(
    const float* __restrict__ src, unsigned short* __restrict__ dst,
    int R, int Ccols)
{
  __shared__ float t[32][33];
  const int c0 = blockIdx.x * 32, r0 = blockIdx.y * 32;
  const int tx = threadIdx.x & 31, ty = threadIdx.x >> 5;
#pragma unroll
  for (int i = 0; i < 32; i += 8)
    t[ty + i][tx] = src[(size_t)(r0 + ty + i) * Ccols + c0 + tx];
  __syncthreads();
#pragma unroll
  for (int i = 0; i < 32; i += 8)
    dst[(size_t)(c0 + ty + i) * R + r0 + tx] = f2bf(t[tx][ty + i]);
}

// ====== deep-pipelined GEMM: C[M, NT*256] = A[M,768]bf16 x Bt[NT*256,768]bf16 ======
// BM=256 BN=256 BK=32; 8 waves (2m x 4n), wave tile 128x64 (acc[8][4]);
// double-buffered 64KB LDS -> 2 blocks/CU; stage distance 1, counted vmcnt(4);
// XOR swizzle key (row>>1)&3 (64B rows, 2-way-free); raw s_barrier; setprio; XCD swz.
template <int NT, int C_BF16, int HAS_BIAS>
__global__ __launch_bounds__(512, 4) void gemm_pipe(
    const unsigned short* __restrict__ A, const unsigned short* __restrict__ Bt,
    const float* __restrict__ bias, void* __restrict__ Cptr)
{
  __shared__ unsigned short lds_[32768];   // 2 x (A 8192 u16 + B 8192 u16) = 64 KiB
  const int Kdim = 768, Ndim = NT * 256;
  const int tid = threadIdx.x;
  const int lane = tid & 63, w = tid >> 6;

  // XCD-aware block swizzle (grid = 128*NT, divisible by 8)
  const int id = blockIdx.x;
  const int nwg8 = (128 * NT) >> 3;
  const int sid = (id & 7) * nwg8 + (id >> 3);
  const int row0 = (sid / NT) * 256;
  const int col0 = (sid % NT) * 256;

  // ---- staging: linear LDS dest, inverse-swizzled global source ----
  // per gload call: 128 rows x 64B; thread -> row tid>>2, dest colbyte (tid&3)*16
  // swizzle key = (row>>1)&3 = (tid>>3)&3; src u16 col = ((tid&3) ^ key) * 8
  const int srow = tid >> 2;                                   // 0..127
  const int scol = ((tid & 3) ^ ((tid >> 3) & 3)) << 3;        // u16
  const size_t ag0 = (size_t)(row0 + srow) * Kdim + scol;
  const size_t ag1 = (size_t)(row0 + 128 + srow) * Kdim + scol;
  const size_t bg0 = (size_t)(col0 + srow) * Kdim + scol;
  const size_t bg1 = (size_t)(col0 + 128 + srow) * Kdim + scol;
  const int dst = tid * 8;                                     // u16, linear

#define STAGE_Q(tt) do { \
    unsigned short* Lq_ = lds_ + ((tt) & 1) * 16384; \
    const int kq_ = (tt) * 32; \
    GLOAD_LDS16(A + ag0 + kq_, Lq_ + dst); \
    GLOAD_LDS16(A + ag1 + kq_, Lq_ + 4096 + dst); \
    GLOAD_LDS16(Bt + bg0 + kq_, Lq_ + 8192 + dst); \
    GLOAD_LDS16(Bt + bg1 + kq_, Lq_ + 8192 + 4096 + dst); \
  } while (0)

  // ---- fragment-read constants (swizzled read) ----
  // logical (row, u16 col q*8) lives at u16 col (q ^ ((row>>1)&3))*8; key = (fr>>1)&3
  const int fr = lane & 15, q = lane >> 4;
  const int wm = w >> 2, wn = w & 3;        // wm 0..1 (128 rows), wn 0..3 (64 cols)
  const int sl = ((q ^ ((fr >> 1) & 3)) << 3);      // u16 col offset
  const int abase = (wm * 128 + fr) * 32;           // u16; + m*512
  const int bbase = 8192 + (wn * 64 + fr) * 32;     // u16; + n*512

  f32x4 acc[8][4];
  const f32x4 fz = {0.f, 0.f, 0.f, 0.f};
#pragma unroll
  for (int m = 0; m < 8; ++m)
#pragma unroll
    for (int n = 0; n < 4; ++n) acc[m][n] = fz;

  STAGE_Q(0);

#pragma unroll 1
  for (int t = 0; t < 24; ++t) {
    if (t < 23) {
      STAGE_Q(t + 1);
      asm volatile("s_waitcnt vmcnt(4)" ::: "memory");
    } else {
      asm volatile("s_waitcnt vmcnt(0)" ::: "memory");
    }
    __builtin_amdgcn_sched_barrier(0);
    __builtin_amdgcn_s_barrier();
    __builtin_amdgcn_sched_barrier(0);

    const unsigned short* Lb = lds_ + (t & 1) * 16384;
    bf16x8 av[8], bv[4];
#pragma unroll
    for (int m = 0; m < 8; ++m)
      av[m] = *(const bf16x8*)&Lb[abase + m * 512 + sl];
#pragma unroll
    for (int n = 0; n < 4; ++n)
      bv[n] = *(const bf16x8*)&Lb[bbase + n * 512 + sl];
    __builtin_amdgcn_s_setprio(1);
#pragma unroll
    for (int m = 0; m < 8; ++m)
#pragma unroll
      for (int n = 0; n < 4; ++n)
        acc[m][n] = __builtin_amdgcn_mfma_f32_16x16x32_bf16(av[m], bv[n], acc[m][n], 0, 0, 0);
    __builtin_amdgcn_s_setprio(0);
    __builtin_amdgcn_sched_barrier(0);
    __builtin_amdgcn_s_barrier();
    __builtin_amdgcn_sched_barrier(0);
  }
#undef STAGE_Q

  const int orow = q * 4;
#pragma unroll
  for (int m = 0; m < 8; ++m) {
#pragma unroll
    for (int n = 0; n < 4; ++n) {
      const int c = col0 + wn * 64 + n * 16 + fr;
      float badd = 0.f;
      if constexpr (HAS_BIAS) badd = bias[c];
#pragma unroll
      for (int j = 0; j < 4; ++j) {
        const int r = row0 + wm * 128 + m * 16 + orow + j;
        float v = acc[m][n][j] + badd;
        if constexpr (C_BF16)
          ((unsigned short*)Cptr)[(size_t)r * Ndim + c] = f2bf(v);
        else
          ((float*)Cptr)[(size_t)r * Ndim + c] = v;
      }
    }
  }
}

__global__ __launch_bounds__(256) void kmax_reduce(
    const float* __restrict__ bmax, float* __restrict__ kmaxp, int n)
{
  __shared__ float red[4];
  float v = NEG_INF;
  for (int i = threadIdx.x; i < n; i += 256) v = fmaxf(v, bmax[i]);
#pragma unroll
  for (int off = 32; off >= 1; off >>= 1) v = fmaxf(v, __shfl_xor(v, off));
  if ((threadIdx.x & 63) == 0) red[threadIdx.x >> 6] = v;
  __syncthreads();
  if (threadIdx.x == 0)
    kmaxp[0] = DN * fmaxf(fmaxf(red[0], red[1]), fmaxf(red[2], red[3]));
}

// ---- K3 (merged): unstabilized k-features -> U=[exp.V], u=[exp], W=[sum V],
//      plus raw-S max tracking. e^{-stab}/eps applied exactly in kv_reduce2.
__global__ __launch_bounds__(256) void kv_partial_mfma(
    const unsigned short* __restrict__ qkv, const unsigned short* __restrict__ Pbf,
    float* __restrict__ kvpart, float* __restrict__ ksumpart,
    float* __restrict__ bmax, float* __restrict__ Wpart)
{
  __shared__ unsigned short K_lds[64 * KVS];     //  9216 B
  __shared__ unsigned short Vt_lds[64 * KVS];    //  9216 B (col ^ (d>>4)<<4)
  __shared__ unsigned short k1_lds[272 * K1S];   // 21760 B (per-ks half, col ^ (lr>>3)<<4)
  __shared__ float diag_lds[64];                 //   256 B
  const int tid = threadIdx.x;
  const int w = tid >> 6, lane = tid & 63;
  const int lr = lane & 15, q = lane >> 4;
  const int bh = blockIdx.x, chunk = blockIdx.y, z = blockIdx.z;
  const int b = bh / H_, h = bh % H_;
  const int ms = z * 8 + 2 * w;
  const int mc = (z == 1 && w == 3) ? 3 : 2;
  const int sn = 16 * w + (lane >> 2);
  const int sd0 = (lane & 3) * 16;
  const int vswz = sn ^ ((lane & 3) << 4);
  const int kswz = (lr >> 3) << 4;
  const f32x4 fz = {0.f, 0.f, 0.f, 0.f};

  f32x4 kvacc[3][4];
  float ksacc[3];
#pragma unroll
  for (int i = 0; i < 3; ++i) {
    ksacc[i] = 0.f;
#pragma unroll
    for (int dt = 0; dt < 4; ++dt) kvacc[i][dt] = fz;
  }
  float mx = NEG_INF;
  float vsum[16];
#pragma unroll
  for (int j = 0; j < 16; ++j) vsum[j] = 0.f;

  bf16x8 pf0[3], pf1[3];
#pragma unroll
  for (int i = 0; i < 3; ++i) {
    const unsigned short* prow = Pbf + (size_t)((ms + i) * 16 + lr) * 64 + q * 8;
    pf0[i] = *(const bf16x8*)prow;
    pf1[i] = *(const bf16x8*)(prow + 32);
  }

  const unsigned short* kbase = qkv + (size_t)(b * N_TOK + chunk * 512 + sn) * TC_ + C_ + h * HD_ + sd0;
  const size_t gstep = (size_t)64 * TC_;

  auto write_buf = [&](int4 wka, int4 wkb, int4 wva, int4 wvb) {
    *(int4*)&K_lds[sn * KVS + sd0] = wka;
    *(int4*)&K_lds[sn * KVS + sd0 + 8] = wkb;
    float sq = 0.f;
    const unsigned short* pk0 = (const unsigned short*)&wka;
#pragma unroll
    for (int j = 0; j < 8; ++j) { float f = bf2f(pk0[j]); sq = fmaf(f, f, sq); }
    const unsigned short* pk1 = (const unsigned short*)&wkb;
#pragma unroll
    for (int j = 0; j < 8; ++j) { float f = bf2f(pk1[j]); sq = fmaf(f, f, sq); }
    sq += __shfl_xor(sq, 1);
    sq += __shfl_xor(sq, 2);
    if ((lane & 3) == 0) diag_lds[sn] = 0.0625f * sq;
    const unsigned short* pv0 = (const unsigned short*)&wva;
    const unsigned short* pv1 = (const unsigned short*)&wvb;
#pragma unroll
    for (int j = 0; j < 8; ++j) {
      float vf = bf2f(pv0[j]);
      vsum[j] += vf;
      Vt_lds[(sd0 + j) * KVS + vswz] = pv0[j];
    }
#pragma unroll
    for (int j = 0; j < 8; ++j) {
      float vf = bf2f(pv1[j]);
      vsum[8 + j] += vf;
      Vt_lds[(sd0 + 8 + j) * KVS + vswz] = pv1[j];
    }
  };

  int4 ka = *(const int4*)kbase;
  int4 kb = *(const int4*)(kbase + 8);
  int4 va = *(const int4*)(kbase + C_);
  int4 vb = *(const int4*)(kbase + C_ + 8);
  write_buf(ka, kb, va, vb);
  asm volatile("s_waitcnt lgkmcnt(0)" ::: "memory");
  __builtin_amdgcn_s_barrier();

#pragma unroll 1
  for (int g = 0; g < 8; ++g) {
    if (g < 7) {
      const unsigned short* kr = kbase + (size_t)(g + 1) * gstep;
      ka = *(const int4*)kr;
      kb = *(const int4*)(kr + 8);
      va = *(const int4*)(kr + C_);
      vb = *(const int4*)(kr + C_ + 8);
    }
    __builtin_amdgcn_sched_barrier(0);

#pragma unroll
    for (int ks = 0; ks < 2; ++ks) {
      bf16x8 bkl[2][2];
#pragma unroll
      for (int t = 0; t < 2; ++t) {
        const int nrow = ((2 * ks + t) * 16 + lr) * KVS;
        bkl[t][0] = *(const bf16x8*)&K_lds[nrow + q * 8];
        bkl[t][1] = *(const bf16x8*)&K_lds[nrow + 32 + q * 8];
      }
      bf16x8 bv[4];
#pragma unroll
      for (int dt = 0; dt < 4; ++dt)
        bv[dt] = *(const bf16x8*)&Vt_lds[(dt * 16 + lr) * KVS + ((ks * 32 + q * 8) ^ (dt << 4))];

#pragma unroll
      for (int i = 0; i < 3; ++i) {
        if (i >= mc) continue;
        const int mt = ms + i;
        const int m = mt * 16 + lr;
        const int mrow = (mt * 16 + lr) * K1S;
        float loc = 0.f;
#pragma unroll
        for (int t = 0; t < 2; ++t) {
          f32x4 s = fz;
          s = __builtin_amdgcn_mfma_f32_16x16x32_bf16(bkl[t][0], pf0[i], s, 0, 0, 0);
          s = __builtin_amdgcn_mfma_f32_16x16x32_bf16(bkl[t][1], pf1[i], s, 0, 0, 0);
          if (m < M_)
            mx = fmaxf(mx, fmaxf(fmaxf(s[0], s[1]), fmaxf(s[2], s[3])));
          ushort4 uo;
          unsigned short* puo = (unsigned short*)&uo;
#pragma unroll
          for (int j = 0; j < 4; ++j) {
            const int nl = (2 * ks + t) * 16 + q * 4 + j;
            float k1f = 0.f;
            if (m < M_) {
              float dash = DN * s[j];
              k1f = __expf(dash - diag_lds[nl]);
            }
            loc += k1f;
            puo[j] = f2bf(k1f);
          }
          *(ushort4*)&k1_lds[mrow + ((t * 16 + q * 4) ^ kswz)] = uo;
        }
        ksacc[i] += loc;
        bf16x8 a1 = *(const bf16x8*)&k1_lds[mrow + ((q * 8) ^ kswz)];
#pragma unroll
        for (int dt = 0; dt < 4; ++dt)
          kvacc[i][dt] = __builtin_amdgcn_mfma_f32_16x16x32_bf16(a1, bv[dt], kvacc[i][dt], 0, 0, 0);
      }
    }

    if (g < 7) {
      __builtin_amdgcn_sched_barrier(0);
      __builtin_amdgcn_s_barrier();
      __builtin_amdgcn_sched_barrier(0);
      write_buf(ka, kb, va, vb);
      asm volatile("s_waitcnt lgkmcnt(0)" ::: "memory");
      __builtin_amdgcn_sched_barrier(0);
      __builtin_amdgcn_s_barrier();
      __builtin_amdgcn_sched_barrier(0);
    }
  }

  const size_t cb = (size_t)(chunk * BH_ + bh) * 64;
#pragma unroll
  for (int i = 0; i < 3; ++i) {
    if (i >= mc) continue;
    const int mt = ms + i;
#pragma unroll
    for (int dt = 0; dt < 4; ++dt) {
      float4 v4;
      v4.x = kvacc[i][dt][0]; v4.y = kvacc[i][dt][1];
      v4.z = kvacc[i][dt][2]; v4.w = kvacc[i][dt][3];
      *(float4*)&kvpart[(cb + dt * 16 + lr) * M2 + mt * 16 + q * 4] = v4;
    }
    float s = ksacc[i];
    s += __shfl_xor(s, 16);
    s += __shfl_xor(s, 32);
    if (lane < 16)
      ksumpart[(size_t)(chunk * BH_ + bh) * M2 + mt * 16 + lane] = s;
  }

#pragma unroll
  for (int off = 32; off >= 1; off >>= 1) mx = fmaxf(mx, __shfl_xor(mx, off));
#pragma unroll
  for (int j = 0; j < 16; ++j) {
    vsum[j] += __shfl_xor(vsum[j], 4);
    vsum[j] += __shfl_xor(vsum[j], 8);
    vsum[j] += __shfl_xor(vsum[j], 16);
    vsum[j] += __shfl_xor(vsum[j], 32);
  }
  __syncthreads();
  float* red = (float*)diag_lds;
  float* Wred = (float*)k1_lds;
  if (lane == 0) red[w] = mx;
  if (lane < 4) {
#pragma unroll
    for (int j = 0; j < 16; ++j)
      Wred[w * 64 + lane * 16 + j] = vsum[j];
  }
  __syncthreads();
  if (tid == 0)
    bmax[(z * 8 + chunk) * BH_ + bh] = fmaxf(fmaxf(red[0], red[1]), fmaxf(red[2], red[3]));
  if (z == 0 && tid < 64)
    Wpart[(size_t)(chunk * BH_ + bh) * 64 + tid] =
        Wred[tid] + Wred[64 + tid] + Wred[128 + tid] + Wred[192 + tid];
}

// ---------------- K4: reduce partials; apply e^{-stab} and eps exactly --------
__global__ __launch_bounds__(256) void kv_reduce2(
    const float* __restrict__ kvpart, const float* __restrict__ ksumpart,
    const float* __restrict__ Wpart, const float* __restrict__ kmaxp,
    unsigned short* __restrict__ kvt_g, float* __restrict__ ksum_g)
{
  const int KVN = BH_ * 64 * M2;
  const int KSN = BH_ * M2;
  const float es = __expf(-kmaxp[0]);
  int idx = blockIdx.x * 256 + threadIdx.x;
  if (idx < KVN) {
    int m = idx % M2;
    float s = 0.f;
    if (m < M_) {
      float U = 0.f;
#pragma unroll
      for (int c = 0; c < 8; ++c) U += kvpart[(size_t)c * KVN + idx];
      const int d = (idx / M2) & 63;
      const int bh = idx / (M2 * 64);
      float Wsum = 0.f;
#pragma unroll
      for (int c = 0; c < 8; ++c) Wsum += Wpart[(size_t)(c * BH_ + bh) * 64 + d];
      s = RATIO * (es * U + FEPS * Wsum);
    }
    kvt_g[idx] = f2bf(s);
  } else if (idx < KVN + KSN) {
    int j = idx - KVN;
    int m = j % M2;
    float s = 0.f;
    if (m < M_) {
      float u = 0.f;
#pragma unroll
      for (int c = 0; c < 8; ++c) u += ksumpart[(size_t)c * KSN + j];
      s = RATIO * (es * u + FEPS * (float)N_TOK);
    }
    ksum_g[j] = s;
  }
}

// ---------------- K5: MFMA q-features + PV + normalize ----------------
__global__ __launch_bounds__(256) void attn_mfma(
    const unsigned short* __restrict__ qkv, const unsigned short* __restrict__ Pbf,
    const unsigned short* __restrict__ kvt_g, const float* __restrict__ ksum_g,
    unsigned short* __restrict__ attn)
{
  __shared__ unsigned short q1_lds[64 * MP];
  __shared__ unsigned short kvt_lds[64 * MP];
  __shared__ float ksum_lds[M2];
  __shared__ float z_lds[64];
  const int tid = threadIdx.x;
  const int bh = blockIdx.x, qt = blockIdx.y;
  const int b = bh / H_, h = bh % H_;
  const int n0 = qt * 64;
  const int w = tid >> 6, lane = tid & 63;
  const int lr = lane & 15, q = lane >> 4;

  {
    const unsigned short* src = kvt_g + (size_t)bh * 64 * M2;
#pragma unroll
    for (int i = 0; i < 9; ++i) {
      int chunk = i * 256 + tid;
      int r = chunk / 36, c = (chunk % 36) * 8;
      *(int4*)&kvt_lds[r * MP + c] = *(const int4*)(src + r * M2 + c);
    }
    if (tid < 72)
      *(float4*)&ksum_lds[tid * 4] = *(const float4*)(ksum_g + (size_t)bh * M2 + tid * 4);
    if (tid < 64) {
      const int4 z4 = {0, 0, 0, 0};
      *(int4*)&q1_lds[tid * MP + 272] = z4;
      *(int4*)&q1_lds[tid * MP + 280] = z4;
    }
  }
  __syncthreads();

  const unsigned short* qrow = qkv + (size_t)(b * N_TOK + n0 + w * 16 + lr) * TC_ + h * HD_;
  bf16x8 bq0 = *(const bf16x8*)(qrow + q * 8);
  bf16x8 bq1 = *(const bf16x8*)(qrow + q * 8 + 32);
  float sq = 0.f;
  {
    const unsigned short* p0 = (const unsigned short*)&bq0;
    const unsigned short* p1 = (const unsigned short*)&bq1;
#pragma unroll
    for (int j = 0; j < 8; ++j) { float f = bf2f(p0[j]); sq = fmaf(f, f, sq); }
#pragma unroll
    for (int j = 0; j < 8; ++j) { float f = bf2f(p1[j]); sq = fmaf(f, f, sq); }
  }
  sq += __shfl_xor(sq, 16);
  sq += __shfl_xor(sq, 32);
  const float diag = 0.0625f * sq;

  f32x4 sacc[17];
  const f32x4 fz = {0.f, 0.f, 0.f, 0.f};
#pragma unroll
  for (int mt = 0; mt < 17; ++mt) sacc[mt] = fz;
#pragma unroll
  for (int mt = 0; mt < 17; ++mt) {
    const unsigned short* prow = Pbf + (size_t)(mt * 16 + lr) * 64;
    bf16x8 ap0 = *(const bf16x8*)(prow + q * 8);
    bf16x8 ap1 = *(const bf16x8*)(prow + q * 8 + 32);
    sacc[mt] = __builtin_amdgcn_mfma_f32_16x16x32_bf16(ap0, bq0, sacc[mt], 0, 0, 0);
    sacc[mt] = __builtin_amdgcn_mfma_f32_16x16x32_bf16(ap1, bq1, sacc[mt], 0, 0, 0);
  }

  float mxr = NEG_INF;
#pragma unroll
  for (int mt = 0; mt < 17; ++mt) {
#pragma unroll
    for (int j = 0; j < 4; ++j) {
      int m = mt * 16 + q * 4 + j;
      if (m < M_) mxr = fmaxf(mxr, sacc[mt][j]);
    }
  }
  mxr = fmaxf(mxr, __shfl_xor(mxr, 16));
  mxr = fmaxf(mxr, __shfl_xor(mxr, 32));
  const float mxd = DN * mxr;

  float zp = 0.f;
#pragma unroll
  for (int mt = 0; mt < 17; ++mt) {
    ushort4 uo;
    unsigned short* puo = (unsigned short*)&uo;
#pragma unroll
    for (int j = 0; j < 4; ++j) {
      const int m = mt * 16 + q * 4 + j;
      float q1f = 0.f;
      if (m < M_) {
        float dash = DN * sacc[mt][j];
        q1f = RATIO * (__expf(dash - diag - mxd) + FEPS);
      }
      zp = fmaf(q1f, ksum_lds[m], zp);
      puo[j] = f2bf(q1f);
    }
    *(ushort4*)&q1_lds[(w * 16 + lr) * MP + mt * 16 + q * 4] = uo;
  }
  zp += __shfl_xor(zp, 16);
  zp += __shfl_xor(zp, 32);
  if (q == 0) z_lds[w * 16 + lr] = 1.0f / zp;

  f32x4 oacc[4];
#pragma unroll
  for (int dt = 0; dt < 4; ++dt) oacc[dt] = fz;
#pragma unroll
  for (int ks = 0; ks < 9; ++ks) {
    bf16x8 aq = *(const bf16x8*)&q1_lds[(w * 16 + lr) * MP + ks * 32 + q * 8];
#pragma unroll
    for (int dt = 0; dt < 4; ++dt) {
      bf16x8 bkv = *(const bf16x8*)&kvt_lds[(dt * 16 + lr) * MP + ks * 32 + q * 8];
      oacc[dt] = __builtin_amdgcn_mfma_f32_16x16x32_bf16(aq, bkv, oacc[dt], 0, 0, 0);
    }
  }

  float zz[4];
#pragma unroll
  for (int j = 0; j < 4; ++j) zz[j] = z_lds[w * 16 + q * 4 + j];
#pragma unroll
  for (int dt = 0; dt < 4; ++dt) {
#pragma unroll
    for (int j = 0; j < 4; ++j) {
      const int r = b * N_TOK + n0 + w * 16 + q * 4 + j;
      attn[(size_t)r * C_ + h * HD_ + dt * 16 + lr] = f2bf(oacc[dt][j] * zz[j]);
    }
  }
}

extern "C" void kernel_launch(void* const* d_in, const int* in_sizes, int n_in,
                              void* d_out, int out_size, void* d_ws, size_t ws_size,
                              hipStream_t stream) {
  const float* x     = (const float*)d_in[0];
  const float* Wqkv  = (const float*)d_in[1];
  const float* Wproj = (const float*)d_in[2];
  const float* bproj = (const float*)d_in[3];
  const float* P     = (const float*)d_in[4];
  float* out = (float*)d_out;
  float* ws = (float*)d_ws;

  // ws layout (f32 words), total ~54.28M words = 217.1 MiB
  unsigned short* qkv    = (unsigned short*)ws;                 // [0, 37748736)
  unsigned short* xb     = (unsigned short*)(ws + 37748736);    // 12,582,912 w
  float*          kvpart = ws + 37748736;                       // 14,155,776 w
  unsigned short* attn   = (unsigned short*)(ws + 37748736);    // 12,582,912 w
  float* ksumpart = ws + 51904512;                              // 221,184 w
  unsigned short* kvt_g  = (unsigned short*)(ws + 52125696);    // 884,736 w
  float* ksum_g   = ws + 53010432;                              // 27,648 w
  float* bmax     = ws + 53038080;                              // 3,072 w
  float* kmaxp    = ws + 53041152;                              // 64 w
  unsigned short* Pbf    = (unsigned short*)(ws + 53041216);    // 9,216 w
  unsigned short* Wqkvt  = (unsigned short*)(ws + 53050432);    // 884,736 w
  unsigned short* Wprojt = (unsigned short*)(ws + 53935168);    // 294,912 w
  float* Wpart    = ws + 54230080;                              // 49,152 w

  cast_bf16<<<dim3(24576), 256, 0, stream>>>(x, xb, ROWS_ * C_);
  transpose_cast<<<dim3(72, 24), 256, 0, stream>>>(Wqkv, Wqkvt, C_, TC_);
  transpose_cast<<<dim3(24, 24), 256, 0, stream>>>(Wproj, Wprojt, C_, C_);
  cast_pbf<<<dim3(72), 256, 0, stream>>>(P, Pbf);

  gemm_pipe<9, 1, 0><<<dim3(1152), 512, 0, stream>>>(xb, Wqkvt, nullptr, qkv);
  kv_partial_mfma<<<dim3(96, 8, 2), 256, 0, stream>>>(qkv, Pbf, kvpart, ksumpart, bmax, Wpart);
  kmax_reduce<<<dim3(1), 256, 0, stream>>>(bmax, kmaxp, 1536);
  kv_reduce2<<<dim3(7020), 256, 0, stream>>>(kvpart, ksumpart, Wpart, kmaxp, kvt_g, ksum_g);
  attn_mfma<<<dim3(96, 64), 256, 0, stream>>>(qkv, Pbf, kvt_g, ksum_g, attn);
  gemm_pipe<3, 0, 1><<<dim3(384), 512, 0, stream>>>(attn, Wprojt, bproj, out);
}

// Round 15
// 448.290 us; speedup vs baseline: 4.5595x; 4.5595x over previous
//
#include <hip/hip_runtime.h>
#include <hip/hip_bf16.h>
#include <math.h>

#define B_ 8
#define N_TOK 4096
#define C_ 768
#define H_ 12
#define HD_ 64
#define M_ 266
#define TC_ 2304
#define BH_ 96
#define ROWS_ 32768

#define M2 288          // padded m-dim (9 ksteps x 32)
#define MP 296          // LDS m-stride (u16), 16B-aligned rows
#define KVS 72          // LDS stride for K/Vt (u16), 16B-aligned rows
#define K1S 40          // LDS stride for k1 half-buffer (u16)

#define DN 0.35355339059327373f      // 1/sqrt(sqrt(64))
#define RATIO 0.06131393394849658f   // 1/sqrt(266)
#define FEPS 1e-4f
#define NEG_INF -3.0e38f

typedef __attribute__((ext_vector_type(4))) float f32x4;
typedef __attribute__((ext_vector_type(8))) short bf16x8;

__device__ __forceinline__ float bf2f(unsigned short u) {
  return __uint_as_float(((unsigned int)u) << 16);
}
__device__ __forceinline__ unsigned short f2bf(float f) {
  unsigned int x = __float_as_uint(f);
  unsigned int r = (x + 0x7fffu + ((x >> 16) & 1u)) >> 16;
  return (unsigned short)r;
}

#define GLOAD_LDS16(g, l) \
  __builtin_amdgcn_global_load_lds( \
      (const __attribute__((address_space(1))) void*)(g), \
      (__attribute__((address_space(3))) void*)(l), 16, 0, 0)

// ---------------- prep: cast f32 -> bf16 elementwise ----------------
__global__ __launch_bounds__(256) void cast_bf16(
    const float* __restrict__ src, unsigned short* __restrict__ dst, int n)
{
  int i = (blockIdx.x * 256 + threadIdx.x) * 4;
  if (i < n) {
    float4 v = *(const float4*)&src[i];
    ushort4 u;
    u.x = f2bf(v.x); u.y = f2bf(v.y); u.z = f2bf(v.z); u.w = f2bf(v.w);
    *(ushort4*)&dst[i] = u;
  }
}

// ---------------- prep: P [266][64] f32 -> Pbf [288][64] bf16 (zero-padded) ----
__global__ __launch_bounds__(256) void cast_pbf(
    const float* __restrict__ P, unsigned short* __restrict__ Pbf)
{
  int idx = blockIdx.x * 256 + threadIdx.x;
  if (idx < M2 * 64) {
    int m = idx >> 6;
    Pbf[idx] = (m < M_) ? f2bf(P[idx]) : (unsigned short)0;
  }
}

// ---------------- prep: transpose + cast: src[R][Ccols] f32 -> dst[Ccols][R] bf16 ----
__global__ __launch_bounds__(256) void transpose_cast(
    const float* __restrict__ src, unsigned short* __restrict__ dst,
    int R, int Ccols)
{
  __shared__ float t[32][33];
  const int c0 = blockIdx.x * 32, r0 = blockIdx.y * 32;
  const int tx = threadIdx.x & 31, ty = threadIdx.x >> 5;
#pragma unroll
  for (int i = 0; i < 32; i += 8)
    t[ty + i][tx] = src[(size_t)(r0 + ty + i) * Ccols + c0 + tx];
  __syncthreads();
#pragma unroll
  for (int i = 0; i < 32; i += 8)
    dst[(size_t)(c0 + ty + i) * R + r0 + tx] = f2bf(t[tx][ty + i]);
}

// ====== deep-pipelined GEMM: C[M, NT*256] = A[M,768]bf16 x Bt[NT*256,768]bf16 ======
// BM=256 BN=256 BK=64; 8 waves (2m x 4n), wave tile 128x64 (acc[8][4]);
// double-buffered 128KB LDS, stage distance 1, counted vmcnt(8);
// 3-bit XOR swizzle byte^=(row&7)<<4; raw s_barrier; setprio; XCD swizzle.
// NOTE: no min-waves launch bound — forcing 4 waves/EU spills acc[8][4] (round-14 lesson).
template <int NT, int C_BF16, int HAS_BIAS>
__global__ __launch_bounds__(512) void gemm_pipe(
    const unsigned short* __restrict__ A, const unsigned short* __restrict__ Bt,
    const float* __restrict__ bias, void* __restrict__ Cptr)
{
  __shared__ unsigned short lds_[65536];   // 2 x (A 16384 u16 + B 16384 u16) = 128 KiB
  const int Kdim = 768, Ndim = NT * 256;
  const int tid = threadIdx.x;
  const int lane = tid & 63, w = tid >> 6;

  const int id = blockIdx.x;
  const int nwg8 = (128 * NT) >> 3;
  const int sid = (id & 7) * nwg8 + (id >> 3);
  const int row0 = (sid / NT) * 256;
  const int col0 = (sid % NT) * 256;

  const int srow = tid >> 3;                                // 0..63
  const int skb = (((tid & 7) ^ (srow & 7)) << 4);          // byte; /2 -> u16
  const size_t ag0 = (size_t)(row0 + srow) * Kdim + (skb >> 1);
  const size_t ag1 = (size_t)(row0 + 64 + srow) * Kdim + (skb >> 1);
  const size_t ag2 = (size_t)(row0 + 128 + srow) * Kdim + (skb >> 1);
  const size_t ag3 = (size_t)(row0 + 192 + srow) * Kdim + (skb >> 1);
  const size_t bg0 = (size_t)(col0 + srow) * Kdim + (skb >> 1);
  const size_t bg1 = (size_t)(col0 + 64 + srow) * Kdim + (skb >> 1);
  const size_t bg2 = (size_t)(col0 + 128 + srow) * Kdim + (skb >> 1);
  const size_t bg3 = (size_t)(col0 + 192 + srow) * Kdim + (skb >> 1);
  const int dst = tid * 8;                                  // u16

#define STAGE_Q(tt) do { \
    unsigned short* Lq_ = lds_ + ((tt) & 1) * 32768; \
    const int kq_ = (tt) * 64; \
    GLOAD_LDS16(A + ag0 + kq_, Lq_ + 0 * 4096 + dst); \
    GLOAD_LDS16(A + ag1 + kq_, Lq_ + 1 * 4096 + dst); \
    GLOAD_LDS16(A + ag2 + kq_, Lq_ + 2 * 4096 + dst); \
    GLOAD_LDS16(A + ag3 + kq_, Lq_ + 3 * 4096 + dst); \
    GLOAD_LDS16(Bt + bg0 + kq_, Lq_ + 16384 + 0 * 4096 + dst); \
    GLOAD_LDS16(Bt + bg1 + kq_, Lq_ + 16384 + 1 * 4096 + dst); \
    GLOAD_LDS16(Bt + bg2 + kq_, Lq_ + 16384 + 2 * 4096 + dst); \
    GLOAD_LDS16(Bt + bg3 + kq_, Lq_ + 16384 + 3 * 4096 + dst); \
  } while (0)

  const int fr = lane & 15, q = lane >> 4;
  const int wm = w >> 2, wn = w & 3;
  const int f7 = fr & 7;
  const int sl0 = ((q + 0) ^ f7) << 3;
  const int sl1 = ((q + 4) ^ f7) << 3;
  const int abase = (wm * 128 + fr) * 64;
  const int bbase = 16384 + (wn * 64 + fr) * 64;

  f32x4 acc[8][4];
  const f32x4 fz = {0.f, 0.f, 0.f, 0.f};
#pragma unroll
  for (int m = 0; m < 8; ++m)
#pragma unroll
    for (int n = 0; n < 4; ++n) acc[m][n] = fz;

  STAGE_Q(0);

#pragma unroll 1
  for (int t = 0; t < 12; ++t) {
    if (t < 11) {
      STAGE_Q(t + 1);
      asm volatile("s_waitcnt vmcnt(8)" ::: "memory");
    } else {
      asm volatile("s_waitcnt vmcnt(0)" ::: "memory");
    }
    __builtin_amdgcn_sched_barrier(0);
    __builtin_amdgcn_s_barrier();
    __builtin_amdgcn_sched_barrier(0);

    const unsigned short* Lb = lds_ + (t & 1) * 32768;
#pragma unroll
    for (int ks = 0; ks < 2; ++ks) {
      const int sl = ks ? sl1 : sl0;
      bf16x8 av[8], bv[4];
#pragma unroll
      for (int m = 0; m < 8; ++m)
        av[m] = *(const bf16x8*)&Lb[abase + m * 1024 + sl];
#pragma unroll
      for (int n = 0; n < 4; ++n)
        bv[n] = *(const bf16x8*)&Lb[bbase + n * 1024 + sl];
      __builtin_amdgcn_s_setprio(1);
#pragma unroll
      for (int m = 0; m < 8; ++m)
#pragma unroll
        for (int n = 0; n < 4; ++n)
          acc[m][n] = __builtin_amdgcn_mfma_f32_16x16x32_bf16(av[m], bv[n], acc[m][n], 0, 0, 0);
      __builtin_amdgcn_s_setprio(0);
    }
    __builtin_amdgcn_sched_barrier(0);
    __builtin_amdgcn_s_barrier();
    __builtin_amdgcn_sched_barrier(0);
  }
#undef STAGE_Q

  const int orow = q * 4;
#pragma unroll
  for (int m = 0; m < 8; ++m) {
#pragma unroll
    for (int n = 0; n < 4; ++n) {
      const int c = col0 + wn * 64 + n * 16 + fr;
      float badd = 0.f;
      if constexpr (HAS_BIAS) badd = bias[c];
#pragma unroll
      for (int j = 0; j < 4; ++j) {
        const int r = row0 + wm * 128 + m * 16 + orow + j;
        float v = acc[m][n][j] + badd;
        if constexpr (C_BF16)
          ((unsigned short*)Cptr)[(size_t)r * Ndim + c] = f2bf(v);
        else
          ((float*)Cptr)[(size_t)r * Ndim + c] = v;
      }
    }
  }
}

__global__ __launch_bounds__(256) void kmax_reduce(
    const float* __restrict__ bmax, float* __restrict__ kmaxp, int n)
{
  __shared__ float red[4];
  float v = NEG_INF;
  for (int i = threadIdx.x; i < n; i += 256) v = fmaxf(v, bmax[i]);
#pragma unroll
  for (int off = 32; off >= 1; off >>= 1) v = fmaxf(v, __shfl_xor(v, off));
  if ((threadIdx.x & 63) == 0) red[threadIdx.x >> 6] = v;
  __syncthreads();
  if (threadIdx.x == 0)
    kmaxp[0] = DN * fmaxf(fmaxf(red[0], red[1]), fmaxf(red[2], red[3]));
}

// ---- K3 (merged): unstabilized k-features -> U=[exp.V], u=[exp], W=[sum V],
//      plus raw-S max tracking. e^{-stab}/eps applied exactly in kv_reduce2.
__global__ __launch_bounds__(256) void kv_partial_mfma(
    const unsigned short* __restrict__ qkv, const unsigned short* __restrict__ Pbf,
    float* __restrict__ kvpart, float* __restrict__ ksumpart,
    float* __restrict__ bmax, float* __restrict__ Wpart)
{
  __shared__ unsigned short K_lds[64 * KVS];     //  9216 B
  __shared__ unsigned short Vt_lds[64 * KVS];    //  9216 B (col ^ (d>>4)<<4)
  __shared__ unsigned short k1_lds[272 * K1S];   // 21760 B (per-ks half, col ^ (lr>>3)<<4)
  __shared__ float diag_lds[64];                 //   256 B
  const int tid = threadIdx.x;
  const int w = tid >> 6, lane = tid & 63;
  const int lr = lane & 15, q = lane >> 4;
  const int bh = blockIdx.x, chunk = blockIdx.y, z = blockIdx.z;
  const int b = bh / H_, h = bh % H_;
  const int ms = z * 8 + 2 * w;
  const int mc = (z == 1 && w == 3) ? 3 : 2;
  const int sn = 16 * w + (lane >> 2);
  const int sd0 = (lane & 3) * 16;
  const int vswz = sn ^ ((lane & 3) << 4);
  const int kswz = (lr >> 3) << 4;
  const f32x4 fz = {0.f, 0.f, 0.f, 0.f};

  f32x4 kvacc[3][4];
  float ksacc[3];
#pragma unroll
  for (int i = 0; i < 3; ++i) {
    ksacc[i] = 0.f;
#pragma unroll
    for (int dt = 0; dt < 4; ++dt) kvacc[i][dt] = fz;
  }
  float mx = NEG_INF;
  float vsum[16];
#pragma unroll
  for (int j = 0; j < 16; ++j) vsum[j] = 0.f;

  bf16x8 pf0[3], pf1[3];
#pragma unroll
  for (int i = 0; i < 3; ++i) {
    const unsigned short* prow = Pbf + (size_t)((ms + i) * 16 + lr) * 64 + q * 8;
    pf0[i] = *(const bf16x8*)prow;
    pf1[i] = *(const bf16x8*)(prow + 32);
  }

  const unsigned short* kbase = qkv + (size_t)(b * N_TOK + chunk * 512 + sn) * TC_ + C_ + h * HD_ + sd0;
  const size_t gstep = (size_t)64 * TC_;

  auto write_buf = [&](int4 wka, int4 wkb, int4 wva, int4 wvb) {
    *(int4*)&K_lds[sn * KVS + sd0] = wka;
    *(int4*)&K_lds[sn * KVS + sd0 + 8] = wkb;
    float sq = 0.f;
    const unsigned short* pk0 = (const unsigned short*)&wka;
#pragma unroll
    for (int j = 0; j < 8; ++j) { float f = bf2f(pk0[j]); sq = fmaf(f, f, sq); }
    const unsigned short* pk1 = (const unsigned short*)&wkb;
#pragma unroll
    for (int j = 0; j < 8; ++j) { float f = bf2f(pk1[j]); sq = fmaf(f, f, sq); }
    sq += __shfl_xor(sq, 1);
    sq += __shfl_xor(sq, 2);
    if ((lane & 3) == 0) diag_lds[sn] = 0.0625f * sq;
    const unsigned short* pv0 = (const unsigned short*)&wva;
    const unsigned short* pv1 = (const unsigned short*)&wvb;
#pragma unroll
    for (int j = 0; j < 8; ++j) {
      float vf = bf2f(pv0[j]);
      vsum[j] += vf;
      Vt_lds[(sd0 + j) * KVS + vswz] = pv0[j];
    }
#pragma unroll
    for (int j = 0; j < 8; ++j) {
      float vf = bf2f(pv1[j]);
      vsum[8 + j] += vf;
      Vt_lds[(sd0 + 8 + j) * KVS + vswz] = pv1[j];
    }
  };

  int4 ka = *(const int4*)kbase;
  int4 kb = *(const int4*)(kbase + 8);
  int4 va = *(const int4*)(kbase + C_);
  int4 vb = *(const int4*)(kbase + C_ + 8);
  write_buf(ka, kb, va, vb);
  asm volatile("s_waitcnt lgkmcnt(0)" ::: "memory");
  __builtin_amdgcn_s_barrier();

#pragma unroll 1
  for (int g = 0; g < 8; ++g) {
    if (g < 7) {
      const unsigned short* kr = kbase + (size_t)(g + 1) * gstep;
      ka = *(const int4*)kr;
      kb = *(const int4*)(kr + 8);
      va = *(const int4*)(kr + C_);
      vb = *(const int4*)(kr + C_ + 8);
    }
    __builtin_amdgcn_sched_barrier(0);

#pragma unroll
    for (int ks = 0; ks < 2; ++ks) {
      bf16x8 bkl[2][2];
#pragma unroll
      for (int t = 0; t < 2; ++t) {
        const int nrow = ((2 * ks + t) * 16 + lr) * KVS;
        bkl[t][0] = *(const bf16x8*)&K_lds[nrow + q * 8];
        bkl[t][1] = *(const bf16x8*)&K_lds[nrow + 32 + q * 8];
      }
      bf16x8 bv[4];
#pragma unroll
      for (int dt = 0; dt < 4; ++dt)
        bv[dt] = *(const bf16x8*)&Vt_lds[(dt * 16 + lr) * KVS + ((ks * 32 + q * 8) ^ (dt << 4))];

#pragma unroll
      for (int i = 0; i < 3; ++i) {
        if (i >= mc) continue;
        const int mt = ms + i;
        const int m = mt * 16 + lr;
        const int mrow = (mt * 16 + lr) * K1S;
        float loc = 0.f;
#pragma unroll
        for (int t = 0; t < 2; ++t) {
          f32x4 s = fz;
          s = __builtin_amdgcn_mfma_f32_16x16x32_bf16(bkl[t][0], pf0[i], s, 0, 0, 0);
          s = __builtin_amdgcn_mfma_f32_16x16x32_bf16(bkl[t][1], pf1[i], s, 0, 0, 0);
          if (m < M_)
            mx = fmaxf(mx, fmaxf(fmaxf(s[0], s[1]), fmaxf(s[2], s[3])));
          ushort4 uo;
          unsigned short* puo = (unsigned short*)&uo;
#pragma unroll
          for (int j = 0; j < 4; ++j) {
            const int nl = (2 * ks + t) * 16 + q * 4 + j;
            float k1f = 0.f;
            if (m < M_) {
              float dash = DN * s[j];
              k1f = __expf(dash - diag_lds[nl]);
            }
            loc += k1f;
            puo[j] = f2bf(k1f);
          }
          *(ushort4*)&k1_lds[mrow + ((t * 16 + q * 4) ^ kswz)] = uo;
        }
        ksacc[i] += loc;
        bf16x8 a1 = *(const bf16x8*)&k1_lds[mrow + ((q * 8) ^ kswz)];
#pragma unroll
        for (int dt = 0; dt < 4; ++dt)
          kvacc[i][dt] = __builtin_amdgcn_mfma_f32_16x16x32_bf16(a1, bv[dt], kvacc[i][dt], 0, 0, 0);
      }
    }

    if (g < 7) {
      __builtin_amdgcn_sched_barrier(0);
      __builtin_amdgcn_s_barrier();
      __builtin_amdgcn_sched_barrier(0);
      write_buf(ka, kb, va, vb);
      asm volatile("s_waitcnt lgkmcnt(0)" ::: "memory");
      __builtin_amdgcn_sched_barrier(0);
      __builtin_amdgcn_s_barrier();
      __builtin_amdgcn_sched_barrier(0);
    }
  }

  const size_t cb = (size_t)(chunk * BH_ + bh) * 64;
#pragma unroll
  for (int i = 0; i < 3; ++i) {
    if (i >= mc) continue;
    const int mt = ms + i;
#pragma unroll
    for (int dt = 0; dt < 4; ++dt) {
      float4 v4;
      v4.x = kvacc[i][dt][0]; v4.y = kvacc[i][dt][1];
      v4.z = kvacc[i][dt][2]; v4.w = kvacc[i][dt][3];
      *(float4*)&kvpart[(cb + dt * 16 + lr) * M2 + mt * 16 + q * 4] = v4;
    }
    float s = ksacc[i];
    s += __shfl_xor(s, 16);
    s += __shfl_xor(s, 32);
    if (lane < 16)
      ksumpart[(size_t)(chunk * BH_ + bh) * M2 + mt * 16 + lane] = s;
  }

#pragma unroll
  for (int off = 32; off >= 1; off >>= 1) mx = fmaxf(mx, __shfl_xor(mx, off));
#pragma unroll
  for (int j = 0; j < 16; ++j) {
    vsum[j] += __shfl_xor(vsum[j], 4);
    vsum[j] += __shfl_xor(vsum[j], 8);
    vsum[j] += __shfl_xor(vsum[j], 16);
    vsum[j] += __shfl_xor(vsum[j], 32);
  }
  __syncthreads();
  float* red = (float*)diag_lds;
  float* Wred = (float*)k1_lds;
  if (lane == 0) red[w] = mx;
  if (lane < 4) {
#pragma unroll
    for (int j = 0; j < 16; ++j)
      Wred[w * 64 + lane * 16 + j] = vsum[j];
  }
  __syncthreads();
  if (tid == 0)
    bmax[(z * 8 + chunk) * BH_ + bh] = fmaxf(fmaxf(red[0], red[1]), fmaxf(red[2], red[3]));
  if (z == 0 && tid < 64)
    Wpart[(size_t)(chunk * BH_ + bh) * 64 + tid] =
        Wred[tid] + Wred[64 + tid] + Wred[128 + tid] + Wred[192 + tid];
}

// ---------------- K4: reduce partials; apply e^{-stab} and eps exactly --------
__global__ __launch_bounds__(256) void kv_reduce2(
    const float* __restrict__ kvpart, const float* __restrict__ ksumpart,
    const float* __restrict__ Wpart, const float* __restrict__ kmaxp,
    unsigned short* __restrict__ kvt_g, float* __restrict__ ksum_g)
{
  const int KVN = BH_ * 64 * M2;
  const int KSN = BH_ * M2;
  const float es = __expf(-kmaxp[0]);
  int idx = blockIdx.x * 256 + threadIdx.x;
  if (idx < KVN) {
    int m = idx % M2;
    float s = 0.f;
    if (m < M_) {
      float U = 0.f;
#pragma unroll
      for (int c = 0; c < 8; ++c) U += kvpart[(size_t)c * KVN + idx];
      const int d = (idx / M2) & 63;
      const int bh = idx / (M2 * 64);
      float Wsum = 0.f;
#pragma unroll
      for (int c = 0; c < 8; ++c) Wsum += Wpart[(size_t)(c * BH_ + bh) * 64 + d];
      s = RATIO * (es * U + FEPS * Wsum);
    }
    kvt_g[idx] = f2bf(s);
  } else if (idx < KVN + KSN) {
    int j = idx - KVN;
    int m = j % M2;
    float s = 0.f;
    if (m < M_) {
      float u = 0.f;
#pragma unroll
      for (int c = 0; c < 8; ++c) u += ksumpart[(size_t)c * KSN + j];
      s = RATIO * (es * u + FEPS * (float)N_TOK);
    }
    ksum_g[j] = s;
  }
}

// ---------------- K5: MFMA q-features + PV + normalize; 4 q-tiles per block ---
__global__ __launch_bounds__(256) void attn_mfma(
    const unsigned short* __restrict__ qkv, const unsigned short* __restrict__ Pbf,
    const unsigned short* __restrict__ kvt_g, const float* __restrict__ ksum_g,
    unsigned short* __restrict__ attn)
{
  __shared__ unsigned short q1_lds[64 * MP];
  __shared__ unsigned short kvt_lds[64 * MP];
  __shared__ float ksum_lds[M2];
  __shared__ float z_lds[64];
  const int tid = threadIdx.x;
  const int bh = blockIdx.x;
  const int b = bh / H_, h = bh % H_;
  const int w = tid >> 6, lane = tid & 63;
  const int lr = lane & 15, q = lane >> 4;
  const f32x4 fz = {0.f, 0.f, 0.f, 0.f};

  {
    const unsigned short* src = kvt_g + (size_t)bh * 64 * M2;
#pragma unroll
    for (int i = 0; i < 9; ++i) {
      int chunk = i * 256 + tid;
      int r = chunk / 36, c = (chunk % 36) * 8;
      *(int4*)&kvt_lds[r * MP + c] = *(const int4*)(src + r * M2 + c);
    }
    if (tid < 72)
      *(float4*)&ksum_lds[tid * 4] = *(const float4*)(ksum_g + (size_t)bh * M2 + tid * 4);
    if (tid < 64) {
      const int4 z4 = {0, 0, 0, 0};
      *(int4*)&q1_lds[tid * MP + 272] = z4;
      *(int4*)&q1_lds[tid * MP + 280] = z4;
    }
  }
  __syncthreads();

#pragma unroll 1
  for (int gq = 0; gq < 4; ++gq) {
    const int n0 = (blockIdx.y * 4 + gq) * 64;

    const unsigned short* qrow = qkv + (size_t)(b * N_TOK + n0 + w * 16 + lr) * TC_ + h * HD_;
    bf16x8 bq0 = *(const bf16x8*)(qrow + q * 8);
    bf16x8 bq1 = *(const bf16x8*)(qrow + q * 8 + 32);
    float sq = 0.f;
    {
      const unsigned short* p0 = (const unsigned short*)&bq0;
      const unsigned short* p1 = (const unsigned short*)&bq1;
#pragma unroll
      for (int j = 0; j < 8; ++j) { float f = bf2f(p0[j]); sq = fmaf(f, f, sq); }
#pragma unroll
      for (int j = 0; j < 8; ++j) { float f = bf2f(p1[j]); sq = fmaf(f, f, sq); }
    }
    sq += __shfl_xor(sq, 16);
    sq += __shfl_xor(sq, 32);
    const float diag = 0.0625f * sq;

    f32x4 sacc[17];
#pragma unroll
    for (int mt = 0; mt < 17; ++mt) sacc[mt] = fz;
#pragma unroll
    for (int mt = 0; mt < 17; ++mt) {
      const unsigned short* prow = Pbf + (size_t)(mt * 16 + lr) * 64;
      bf16x8 ap0 = *(const bf16x8*)(prow + q * 8);
      bf16x8 ap1 = *(const bf16x8*)(prow + q * 8 + 32);
      sacc[mt] = __builtin_amdgcn_mfma_f32_16x16x32_bf16(ap0, bq0, sacc[mt], 0, 0, 0);
      sacc[mt] = __builtin_amdgcn_mfma_f32_16x16x32_bf16(ap1, bq1, sacc[mt], 0, 0, 0);
    }

    float mxr = NEG_INF;
#pragma unroll
    for (int mt = 0; mt < 17; ++mt) {
#pragma unroll
      for (int j = 0; j < 4; ++j) {
        int m = mt * 16 + q * 4 + j;
        if (m < M_) mxr = fmaxf(mxr, sacc[mt][j]);
      }
    }
    mxr = fmaxf(mxr, __shfl_xor(mxr, 16));
    mxr = fmaxf(mxr, __shfl_xor(mxr, 32));
    const float mxd = DN * mxr;

    float zp = 0.f;
#pragma unroll
    for (int mt = 0; mt < 17; ++mt) {
      ushort4 uo;
      unsigned short* puo = (unsigned short*)&uo;
#pragma unroll
      for (int j = 0; j < 4; ++j) {
        const int m = mt * 16 + q * 4 + j;
        float q1f = 0.f;
        if (m < M_) {
          float dash = DN * sacc[mt][j];
          q1f = RATIO * (__expf(dash - diag - mxd) + FEPS);
        }
        zp = fmaf(q1f, ksum_lds[m], zp);
        puo[j] = f2bf(q1f);
      }
      *(ushort4*)&q1_lds[(w * 16 + lr) * MP + mt * 16 + q * 4] = uo;
    }
    zp += __shfl_xor(zp, 16);
    zp += __shfl_xor(zp, 32);
    if (q == 0) z_lds[w * 16 + lr] = 1.0f / zp;

    f32x4 oacc[4];
#pragma unroll
    for (int dt = 0; dt < 4; ++dt) oacc[dt] = fz;
#pragma unroll
    for (int ks = 0; ks < 9; ++ks) {
      bf16x8 aq = *(const bf16x8*)&q1_lds[(w * 16 + lr) * MP + ks * 32 + q * 8];
#pragma unroll
      for (int dt = 0; dt < 4; ++dt) {
        bf16x8 bkv = *(const bf16x8*)&kvt_lds[(dt * 16 + lr) * MP + ks * 32 + q * 8];
        oacc[dt] = __builtin_amdgcn_mfma_f32_16x16x32_bf16(aq, bkv, oacc[dt], 0, 0, 0);
      }
    }

    float zz[4];
#pragma unroll
    for (int j = 0; j < 4; ++j) zz[j] = z_lds[w * 16 + q * 4 + j];
#pragma unroll
    for (int dt = 0; dt < 4; ++dt) {
#pragma unroll
      for (int j = 0; j < 4; ++j) {
        const int r = b * N_TOK + n0 + w * 16 + q * 4 + j;
        attn[(size_t)r * C_ + h * HD_ + dt * 16 + lr] = f2bf(oacc[dt][j] * zz[j]);
      }
    }
  }
}

extern "C" void kernel_launch(void* const* d_in, const int* in_sizes, int n_in,
                              void* d_out, int out_size, void* d_ws, size_t ws_size,
                              hipStream_t stream) {
  const float* x     = (const float*)d_in[0];
  const float* Wqkv  = (const float*)d_in[1];
  const float* Wproj = (const float*)d_in[2];
  const float* bproj = (const float*)d_in[3];
  const float* P     = (const float*)d_in[4];
  float* out = (float*)d_out;
  float* ws = (float*)d_ws;

  // ws layout (f32 words), total ~54.28M words = 217.1 MiB
  unsigned short* qkv    = (unsigned short*)ws;                 // [0, 37748736)
  unsigned short* xb     = (unsigned short*)(ws + 37748736);    // 12,582,912 w
  float*          kvpart = ws + 37748736;                       // 14,155,776 w
  unsigned short* attn   = (unsigned short*)(ws + 37748736);    // 12,582,912 w
  float* ksumpart = ws + 51904512;                              // 221,184 w
  unsigned short* kvt_g  = (unsigned short*)(ws + 52125696);    // 884,736 w
  float* ksum_g   = ws + 53010432;                              // 27,648 w
  float* bmax     = ws + 53038080;                              // 3,072 w
  float* kmaxp    = ws + 53041152;                              // 64 w
  unsigned short* Pbf    = (unsigned short*)(ws + 53041216);    // 9,216 w
  unsigned short* Wqkvt  = (unsigned short*)(ws + 53050432);    // 884,736 w
  unsigned short* Wprojt = (unsigned short*)(ws + 53935168);    // 294,912 w
  float* Wpart    = ws + 54230080;                              // 49,152 w

  cast_bf16<<<dim3(24576), 256, 0, stream>>>(x, xb, ROWS_ * C_);
  transpose_cast<<<dim3(72, 24), 256, 0, stream>>>(Wqkv, Wqkvt, C_, TC_);
  transpose_cast<<<dim3(24, 24), 256, 0, stream>>>(Wproj, Wprojt, C_, C_);
  cast_pbf<<<dim3(72), 256, 0, stream>>>(P, Pbf);

  gemm_pipe<9, 1, 0><<<dim3(1152), 512, 0, stream>>>(xb, Wqkvt, nullptr, qkv);
  kv_partial_mfma<<<dim3(96, 8, 2), 256, 0, stream>>>(qkv, Pbf, kvpart, ksumpart, bmax, Wpart);
  kmax_reduce<<<dim3(1), 256, 0, stream>>>(bmax, kmaxp, 1536);
  kv_reduce2<<<dim3(7020), 256, 0, stream>>>(kvpart, ksumpart, Wpart, kmaxp, kvt_g, ksum_g);
  attn_mfma<<<dim3(96, 16), 256, 0, stream>>>(qkv, Pbf, kvt_g, ksum_g, attn);
  gemm_pipe<3, 0, 1><<<dim3(384), 512, 0, stream>>>(attn, Wprojt, bproj, out);
}